// Round 6
// baseline (27.161 us; speedup 1.0000x reference)
//
#include <hip/hip_runtime.h>
#include <math.h>

#define PN 256
#define BN 1024
#define AN 15
#define NBIN 36
#define NBT 64
#define NRAMA 40
#define CSTRIDE 13            // 12 dwords (atoms 0..3 xyz) + 1 pad
#define PADT 40               // padded rama table dim (rows/cols 0..38 used)
#define PAD_ELEMS (NRAMA * PADT * PADT)
#define SLAB_DW (BN * AN * 3) // 46080 dwords per pose
#define SLAB_V4 (SLAB_DW / 4) // 11520 float4

__device__ __forceinline__ int wrap36(int v) {
    v %= NBIN;
    if (v < 0) v += NBIN;
    return v;
}

__device__ __forceinline__ void crw(float t, float w[4]) {
    float t2 = t * t;
    float t3 = t2 * t;
    w[0] = -0.5f * t3 + t2 - 0.5f * t;
    w[1] =  1.5f * t3 - 2.5f * t2 + 1.0f;
    w[2] = -1.5f * t3 + 2.0f * t2 + 0.5f * t;
    w[3] =  0.5f * t3 - 0.5f * t2;
}

__device__ __forceinline__ void cross3(const float a[3], const float b[3], float o[3]) {
    o[0] = a[1] * b[2] - a[2] * b[1];
    o[1] = a[2] * b[0] - a[0] * b[2];
    o[2] = a[0] * b[1] - a[1] * b[0];
}

__device__ __forceinline__ float dot3(const float a[3], const float b[3]) {
    return a[0] * b[0] + a[1] * b[1] + a[2] * b[2];
}

// atan2 via 5-term minimax atan poly; max err ~1e-4 rad (threshold is 1.33 abs
// on a 1024-term sum -> enormous headroom). mx clamped so (0,0) -> 0, not NaN.
__device__ __forceinline__ float fast_atan2f(float y, float x) {
    float ax = fabsf(x), ay = fabsf(y);
    float mx = fmaxf(fmaxf(ax, ay), 1e-30f);
    float mn = fminf(ax, ay);
    float a  = mn * __builtin_amdgcn_rcpf(mx);
    float s  = a * a;
    float r  = fmaf(fmaf(fmaf(0.0208351f, s, -0.0851330f), s, 0.180141f), s, -0.3302995f);
    r = fmaf(r, s, 0.9998660f) * a;
    if (ay > ax)  r = 1.5707964f - r;
    if (x < 0.0f) r = 3.1415927f - r;
    return copysignf(r, y);
}

// Build wrap-padded rama tables in workspace: pad[r][a][b] = rama[r][(a-1)%36][(b-1)%36]
__global__ __launch_bounds__(256) void build_pad_kernel(
    const float* __restrict__ rama_tables, float* __restrict__ pad)
{
    const int idx = blockIdx.x * 256 + threadIdx.x;
    if (idx >= PAD_ELEMS) return;
    const int r   = idx / (PADT * PADT);
    const int rem = idx - r * (PADT * PADT);
    const int a   = rem / PADT;
    const int b   = rem - a * PADT;
    const int sa  = (a + 35) % 36;
    const int sb  = (b + 35) % 36;
    pad[idx] = rama_tables[(r * NBIN + sa) * NBIN + sb];
}

template <bool USE_PAD>
__global__ __launch_bounds__(1024) void bb_torsion_kernel(
    const float* __restrict__ coords,        // (P, B*A, 3)
    const int*   __restrict__ off,           // (P, B)
    const int*   __restrict__ btype,         // (P, B)
    const int*   __restrict__ conn,          // (P, B, 2, 2)
    const int*   __restrict__ dsc,           // (NBT, 2, 4)
    const int*   __restrict__ rama_tbl_ind,  // (NBT, 2)
    const int*   __restrict__ upper_conn,    // (NBT,)
    const int*   __restrict__ is_pro,        // (NBT,)
    const int*   __restrict__ tor_atoms,     // (NBT, 3, 4, 3)
    const float* __restrict__ rama_tables,   // (40, 36, 36)
    const float* __restrict__ omega_tables,  // (2, 36)
    const float* __restrict__ rama_params,   // (40, 4)
    const float* __restrict__ omega_params,  // (2, 2)
    const float* __restrict__ pad,           // (40, 40, 40) padded copy (or null)
    float*       __restrict__ out)           // (2, P)
{
    const int tid = threadIdx.x;
    const int p   = blockIdx.x;          // one block per pose
    const int pb  = p * BN + tid;

    const float* cp = coords + (size_t)p * SLAB_DW;

    // ---- LDS ----
    __shared__ float cslab[BN * CSTRIDE];   // 53248 B: slab atoms (g%15)<4, keyed by g/15
    __shared__ int   s_bt[BN];              // 4096 B
    __shared__ int   s_off[BN];             // 4096 B
    __shared__ int   s_ta[NBT * 36];        // 9216 B
    __shared__ int   s_dsc[NBT * 8];        // 2048 B
    __shared__ int   s_rti[NBT * 2];        // 512 B
    __shared__ int   s_uc[NBT];             // 256 B
    __shared__ int   s_ip[NBT];             // 256 B
    __shared__ float s_rp[NRAMA * 4];       // 640 B
    __shared__ float s_ot2[2 * PADT];       // 320 B (wrap-padded omega rows)
    __shared__ float s_op[4];               // 16 B
    __shared__ float swr[16], swo[16];

    // ---- staging: contiguous float4 slab copy, demux atoms 0..3 into cslab ----
    {
        const float4* src4 = (const float4*)cp;   // pose base is 16B-aligned
        for (int i = tid; i < SLAB_V4; i += 1024) {
            const float4 v = src4[i];
            const int d0 = 4 * i;
            #pragma unroll
            for (int c = 0; c < 4; ++c) {
                const int d   = d0 + c;
                const int res = d / 45;           // residue slot in slab
                const int rem = d - res * 45;     // dword within residue (0..44)
                if (rem < 12)
                    cslab[res * CSTRIDE + rem] = (c == 0) ? v.x : (c == 1) ? v.y : (c == 2) ? v.z : v.w;
            }
        }
    }
    const int off_r  = off[pb];
    const int bt_raw = btype[pb];
    s_off[tid] = off_r;
    s_bt[tid]  = bt_raw;
    const int4 cn = *(const int4*)(conn + pb * 4);   // own conn row, 16B aligned
    if (tid < NBT * 36) s_ta[tid] = tor_atoms[tid];  // 2304 <= 1024? NO -> loop
    if (tid + 1024 < NBT * 36) s_ta[tid + 1024] = tor_atoms[tid + 1024];
    if (tid + 2048 < NBT * 36) s_ta[tid + 2048] = tor_atoms[tid + 2048];
    if (tid < NBT * 8)   s_dsc[tid] = dsc[tid];
    if (tid < NBT * 2)   s_rti[tid] = rama_tbl_ind[tid];
    if (tid < NBT)       { s_uc[tid] = upper_conn[tid]; s_ip[tid] = is_pro[tid]; }
    if (tid < NRAMA * 4) s_rp[tid] = rama_params[tid];
    if (tid < 2 * PADT)  {                       // wrap-padded omega rows
        const int t = tid / PADT, k = tid - t * PADT;
        s_ot2[tid] = omega_tables[t * NBIN + (k + 35) % 36];
    }
    if (tid < 4)         s_op[tid] = omega_params[tid];
    __syncthreads();

    const bool real = bt_raw >= 0;
    const int  btc  = real ? bt_raw : 0;

    float dih[3];
    bool  tv[3];

    #pragma unroll
    for (int t = 0; t < 3; ++t) {
        float pts[4][3];
        bool  valid = true;
        #pragma unroll
        for (int at = 0; at < 4; ++at) {
            const int tabase  = ((btc * 3 + t) * 4 + at) * 3;
            const int a_ind   = s_ta[tabase + 0];
            const int c_ind   = s_ta[tabase + 1];
            const int n_bonds = s_ta[tabase + 2];
            int  g;
            bool va;
            if (a_ind >= 0) {
                g  = off_r + a_ind;
                va = true;
            } else {
                const int cc        = min(c_ind > 0 ? c_ind : 0, 1);
                const int nbr_block = cc ? cn.z : cn.x;
                const int nbr_conn  = cc ? cn.w : cn.y;
                const int nb        = nbr_block > 0 ? nbr_block : 0;
                int nbt = s_bt[nb];
                if (nbt < 0) nbt = 0;
                const int noff = s_off[nb];
                const int ncc  = min(nbr_conn > 0 ? nbr_conn : 0, 1);
                const int nbb  = min(n_bonds > 0 ? n_bonds : 0, 3);
                const int ds   = s_dsc[(nbt * 2 + ncc) * 4 + nbb];
                g  = noff + ds;
                va = (c_ind >= 0) && (nbr_block >= 0) && (ds >= 0);
            }
            valid = valid && va;
            bool hit = false;
            if ((unsigned)g < (unsigned)(BN * AN)) {
                const int gres = g / 15;
                const int gat  = g - gres * 15;
                if (gat < 4) {
                    const float* s = cslab + gres * CSTRIDE + gat * 3;
                    pts[at][0] = s[0];
                    pts[at][1] = s[1];
                    pts[at][2] = s[2];
                    hit = true;
                }
            }
            if (!hit) {
                int gc = g > 0 ? g : 0;
                if (gc > BN * AN - 1) gc = BN * AN - 1;
                const float* c3 = cp + (size_t)gc * 3;
                pts[at][0] = c3[0];
                pts[at][1] = c3[1];
                pts[at][2] = c3[2];
            }
        }
        tv[t] = valid && real;

        float b1[3], b2[3], b3[3];
        #pragma unroll
        for (int k = 0; k < 3; ++k) {
            b1[k] = pts[1][k] - pts[0][k];
            b2[k] = pts[2][k] - pts[1][k];
            b3[k] = pts[3][k] - pts[2][k];
        }
        float n1[3], n2[3], b2n[3], m1[3];
        cross3(b1, b2, n1);
        cross3(b2, b3, n2);
        const float inv = 1.0f / sqrtf(dot3(b2, b2));
        #pragma unroll
        for (int k = 0; k < 3; ++k) b2n[k] = b2[k] * inv;
        cross3(n1, b2n, m1);
        dih[t] = fast_atan2f(dot3(m1, n2), dot3(n1, n2));
    }

    // ---- rama ----
    int uc = s_uc[btc];
    uc = min(uc < 0 ? 0 : uc, 1);
    const int nxt = uc ? cn.z : cn.x;
    const int nb2 = nxt > 0 ? nxt : 0;
    int nbt2 = s_bt[nb2];
    if (nbt2 < 0) nbt2 = 0;
    const int ipn = (nxt >= 0) ? s_ip[nbt2] : 0;
    const int ri  = s_rti[btc * 2 + ipn];

    const float* rp = s_rp + ri * 4;
    const float x = (dih[0] - rp[0]) * __builtin_amdgcn_rcpf(rp[2]);
    const float y = (dih[1] - rp[1]) * __builtin_amdgcn_rcpf(rp[3]);
    const float ix0 = floorf(x);
    const float iy0 = floorf(y);
    const float fx = x - ix0;
    const float fy = y - iy0;
    const int ixw = wrap36((int)ix0);
    const int iyw = wrap36((int)iy0);

    float wx[4], wy[4];
    crw(fx, wx);
    crw(fy, wy);

    float er = 0.0f;
    if (USE_PAD) {
        const float* tb = pad + (size_t)ri * (PADT * PADT) + ixw * PADT + iyw;
        #pragma unroll
        for (int i = 0; i < 4; ++i) {
            float4 rv;
            __builtin_memcpy(&rv, tb + i * PADT, sizeof(float4));
            er = fmaf(wx[i], wy[0] * rv.x + wy[1] * rv.y + wy[2] * rv.z + wy[3] * rv.w, er);
        }
    } else {
        const float* rt = rama_tables + (size_t)ri * NBIN * NBIN;
        #pragma unroll
        for (int i = 0; i < 4; ++i) {
            const float* rrow = rt + wrap36(ixw + i - 0) * NBIN; // ixw+i may exceed 35
            float rowv = 0.0f;
            #pragma unroll
            for (int j = 0; j < 4; ++j) rowv += wy[j] * rrow[wrap36(iyw + j)];
            er += wx[i] * rowv;
        }
    }
    float r_contrib = (tv[0] && tv[1]) ? er : 0.0f;

    // ---- omega (padded LDS row: no wraps) ----
    const int oi = s_ip[btc];
    const float z = (dih[2] - s_op[oi * 2 + 0]) * __builtin_amdgcn_rcpf(s_op[oi * 2 + 1]);
    const float iz0 = floorf(z);
    const float fz = z - iz0;
    const int izw = wrap36((int)iz0);
    float wz[4];
    crw(fz, wz);
    const float* ot = s_ot2 + oi * PADT + izw;
    float eo = wz[0] * ot[0] + wz[1] * ot[1] + wz[2] * ot[2] + wz[3] * ot[3];
    float o_contrib = tv[2] ? eo : 0.0f;

    // ---- reduce ----
    float r = r_contrib;
    float o = o_contrib;
    #pragma unroll
    for (int d = 32; d > 0; d >>= 1) {
        r += __shfl_down(r, d);
        o += __shfl_down(o, d);
    }
    const int wid = tid >> 6;
    if ((tid & 63) == 0) {
        swr[wid] = r;
        swo[wid] = o;
    }
    __syncthreads();
    if (tid < 64) {
        float R = (tid < 16) ? swr[tid] : 0.0f;
        float O = (tid < 16) ? swo[tid] : 0.0f;
        #pragma unroll
        for (int d = 8; d > 0; d >>= 1) {
            R += __shfl_down(R, d);
            O += __shfl_down(O, d);
        }
        if (tid == 0) {
            out[p]      = R;
            out[PN + p] = O;
        }
    }
}

extern "C" void kernel_launch(void* const* d_in, const int* in_sizes, int n_in,
                              void* d_out, int out_size, void* d_ws, size_t ws_size,
                              hipStream_t stream) {
    const float* coords        = (const float*)d_in[0];
    const int*   off           = (const int*)d_in[1];
    const int*   btype         = (const int*)d_in[2];
    const int*   conn          = (const int*)d_in[3];
    const int*   dsc           = (const int*)d_in[4];
    const int*   rama_tbl_ind  = (const int*)d_in[5];
    const int*   upper_conn    = (const int*)d_in[6];
    const int*   is_pro        = (const int*)d_in[7];
    const int*   tor_atoms     = (const int*)d_in[8];
    const float* rama_tables   = (const float*)d_in[9];
    const float* omega_tables  = (const float*)d_in[10];
    const float* rama_params   = (const float*)d_in[11];
    const float* omega_params  = (const float*)d_in[12];
    float* out = (float*)d_out;

    const bool use_pad = ws_size >= (size_t)PAD_ELEMS * sizeof(float);
    if (use_pad) {
        build_pad_kernel<<<(PAD_ELEMS + 255) / 256, 256, 0, stream>>>(
            rama_tables, (float*)d_ws);
        bb_torsion_kernel<true><<<PN, 1024, 0, stream>>>(
            coords, off, btype, conn, dsc, rama_tbl_ind, upper_conn, is_pro,
            tor_atoms, rama_tables, omega_tables, rama_params, omega_params,
            (const float*)d_ws, out);
    } else {
        bb_torsion_kernel<false><<<PN, 1024, 0, stream>>>(
            coords, off, btype, conn, dsc, rama_tbl_ind, upper_conn, is_pro,
            tor_atoms, rama_tables, omega_tables, rama_params, omega_params,
            nullptr, out);
    }
}

// Round 7
// 23.630 us; speedup vs baseline: 1.1494x; 1.1494x over previous
//
#include <hip/hip_runtime.h>
#include <math.h>

#define PN 256
#define BN 1024
#define AN 15
#define NBIN 36
#define NBT 64
#define NRAMA 40
#define CSTRIDE 13   // 12 dwords (atoms 0..3 xyz) + 1 pad -> coprime with 32 banks
#define PADT 40      // padded omega row length

// 16-byte load with only 4-B alignment guaranteed. If gfx950 unaligned-access
// mode is on (default), LLVM emits one global_load_dwordx4; otherwise it
// legalizes to 4 dword loads. Correct either way.
struct __attribute__((packed, aligned(4))) uf4 { float x, y, z, w; };

__device__ __forceinline__ int wrap36(int v) {
    v %= NBIN;
    if (v < 0) v += NBIN;
    return v;
}

__device__ __forceinline__ void crw(float t, float w[4]) {
    float t2 = t * t;
    float t3 = t2 * t;
    w[0] = -0.5f * t3 + t2 - 0.5f * t;
    w[1] =  1.5f * t3 - 2.5f * t2 + 1.0f;
    w[2] = -1.5f * t3 + 2.0f * t2 + 0.5f * t;
    w[3] =  0.5f * t3 - 0.5f * t2;
}

__device__ __forceinline__ void cross3(const float a[3], const float b[3], float o[3]) {
    o[0] = a[1] * b[2] - a[2] * b[1];
    o[1] = a[2] * b[0] - a[0] * b[2];
    o[2] = a[0] * b[1] - a[1] * b[0];
}

__device__ __forceinline__ float dot3(const float a[3], const float b[3]) {
    return a[0] * b[0] + a[1] * b[1] + a[2] * b[2];
}

// atan2 via minimax atan poly on [0,1]; passed R6 with absmax 0.25 << 1.33.
__device__ __forceinline__ float fast_atan2f(float y, float x) {
    float ax = fabsf(x), ay = fabsf(y);
    float mx = fmaxf(fmaxf(ax, ay), 1e-30f);
    float mn = fminf(ax, ay);
    float a  = mn * __builtin_amdgcn_rcpf(mx);
    float s  = a * a;
    float r  = fmaf(fmaf(fmaf(0.0208351f, s, -0.0851330f), s, 0.180141f), s, -0.3302995f);
    r = fmaf(r, s, 0.9998660f) * a;
    if (ay > ax)  r = 1.5707964f - r;
    if (x < 0.0f) r = 3.1415927f - r;
    return copysignf(r, y);
}

__global__ __launch_bounds__(1024) void bb_torsion_kernel(
    const float* __restrict__ coords,        // (P, B*A, 3)
    const int*   __restrict__ off,           // (P, B)
    const int*   __restrict__ btype,         // (P, B)
    const int*   __restrict__ conn,          // (P, B, 2, 2)
    const int*   __restrict__ dsc,           // (NBT, 2, 4)
    const int*   __restrict__ rama_tbl_ind,  // (NBT, 2)
    const int*   __restrict__ upper_conn,    // (NBT,)
    const int*   __restrict__ is_pro,        // (NBT,)
    const int*   __restrict__ tor_atoms,     // (NBT, 3, 4, 3)
    const float* __restrict__ rama_tables,   // (40, 36, 36)
    const float* __restrict__ omega_tables,  // (2, 36)
    const float* __restrict__ rama_params,   // (40, 4)
    const float* __restrict__ omega_params,  // (2, 2)
    float*       __restrict__ out)           // (2, P)
{
    const int tid = threadIdx.x;
    const int p   = blockIdx.x;          // one block per pose
    const int pb  = p * BN + tid;

    const float* cp = coords + (size_t)p * (BN * AN) * 3;

    // ---- LDS ----
    __shared__ float cslab[BN * CSTRIDE];   // 53248 B
    __shared__ int   s_bt[BN];              // 4096 B
    __shared__ int   s_off[BN];             // 4096 B
    __shared__ int   s_ta[NBT * 36];        // 9216 B
    __shared__ int   s_dsc[NBT * 8];        // 2048 B
    __shared__ int   s_rti[NBT * 2];        // 512 B
    __shared__ int   s_uc[NBT];             // 256 B
    __shared__ int   s_ip[NBT];             // 256 B
    __shared__ float s_rp[NRAMA * 4];       // 640 B
    __shared__ float s_ot2[2 * PADT];       // 320 B (wrap-padded omega rows)
    __shared__ float s_op[4];               // 16 B
    __shared__ float swr[16], swo[16];

    // ---- staging ----
    const int off_r  = off[pb];
    const int bt_raw = btype[pb];
    s_off[tid] = off_r;
    s_bt[tid]  = bt_raw;
    {
        // own residue's atoms 0..3 = 12 consecutive dwords; 3 x 16B loads
        const float* src = cp + (size_t)off_r * 3;
        const uf4 v0 = *(const uf4*)(src);
        const uf4 v1 = *(const uf4*)(src + 4);
        const uf4 v2 = *(const uf4*)(src + 8);
        float* d = cslab + tid * CSTRIDE;
        d[0] = v0.x; d[1] = v0.y; d[2]  = v0.z; d[3]  = v0.w;
        d[4] = v1.x; d[5] = v1.y; d[6]  = v1.z; d[7]  = v1.w;
        d[8] = v2.x; d[9] = v2.y; d[10] = v2.z; d[11] = v2.w;
    }
    const int4 cn = *(const int4*)(conn + pb * 4);   // own conn row, 16B aligned
    if (tid < NBT * 36) s_ta[tid] = tor_atoms[tid];
    if (tid + 1024 < NBT * 36) s_ta[tid + 1024] = tor_atoms[tid + 1024];
    if (tid + 2048 < NBT * 36) s_ta[tid + 2048] = tor_atoms[tid + 2048];
    if (tid < NBT * 8)   s_dsc[tid] = dsc[tid];
    if (tid < NBT * 2)   s_rti[tid] = rama_tbl_ind[tid];
    if (tid < NBT)       { s_uc[tid] = upper_conn[tid]; s_ip[tid] = is_pro[tid]; }
    if (tid < NRAMA * 4) s_rp[tid] = rama_params[tid];
    if (tid < 2 * PADT)  {
        const int t = tid / PADT, k = tid - t * PADT;
        s_ot2[tid] = omega_tables[t * NBIN + (k + 35) % 36];
    }
    if (tid < 4)         s_op[tid] = omega_params[tid];
    __syncthreads();

    const bool real = bt_raw >= 0;
    const int  btc  = real ? bt_raw : 0;

    float dih[3];
    bool  tv[3];

    #pragma unroll
    for (int t = 0; t < 3; ++t) {
        float pts[4][3];
        bool  valid = true;
        #pragma unroll
        for (int at = 0; at < 4; ++at) {
            const int tabase  = ((btc * 3 + t) * 4 + at) * 3;
            const int a_ind   = s_ta[tabase + 0];
            const int c_ind   = s_ta[tabase + 1];
            const int n_bonds = s_ta[tabase + 2];
            int  g;
            bool va;
            if (a_ind >= 0) {
                g  = off_r + a_ind;
                va = true;
            } else {
                const int cc        = min(c_ind > 0 ? c_ind : 0, 1);
                const int nbr_block = cc ? cn.z : cn.x;
                const int nbr_conn  = cc ? cn.w : cn.y;
                const int nb        = nbr_block > 0 ? nbr_block : 0;
                int nbt = s_bt[nb];
                if (nbt < 0) nbt = 0;
                const int noff = s_off[nb];
                const int ncc  = min(nbr_conn > 0 ? nbr_conn : 0, 1);
                const int nbb  = min(n_bonds > 0 ? n_bonds : 0, 3);
                const int ds   = s_dsc[(nbt * 2 + ncc) * 4 + nbb];
                g  = noff + ds;
                va = (c_ind >= 0) && (nbr_block >= 0) && (ds >= 0);
            }
            valid = valid && va;
            bool hit = false;
            if ((unsigned)g < (unsigned)(BN * AN)) {
                const int gres = g / 15;
                const int gat  = g - gres * 15;
                if (gat < 4) {                 // in LDS cache (off[res]==15*res data)
                    const float* s = cslab + gres * CSTRIDE + gat * 3;
                    pts[at][0] = s[0];
                    pts[at][1] = s[1];
                    pts[at][2] = s[2];
                    hit = true;
                }
            }
            if (!hit) {                        // generic fallback
                int gc = g > 0 ? g : 0;
                if (gc > BN * AN - 1) gc = BN * AN - 1;
                const float* c3 = cp + (size_t)gc * 3;
                pts[at][0] = c3[0];
                pts[at][1] = c3[1];
                pts[at][2] = c3[2];
            }
        }
        tv[t] = valid && real;

        float b1[3], b2[3], b3[3];
        #pragma unroll
        for (int k = 0; k < 3; ++k) {
            b1[k] = pts[1][k] - pts[0][k];
            b2[k] = pts[2][k] - pts[1][k];
            b3[k] = pts[3][k] - pts[2][k];
        }
        float n1[3], n2[3], b2n[3], m1[3];
        cross3(b1, b2, n1);
        cross3(b2, b3, n2);
        const float inv = __builtin_amdgcn_rsqf(dot3(b2, b2));
        #pragma unroll
        for (int k = 0; k < 3; ++k) b2n[k] = b2[k] * inv;
        cross3(n1, b2n, m1);
        dih[t] = fast_atan2f(dot3(m1, n2), dot3(n1, n2));
    }

    // ---- rama ----
    int uc = s_uc[btc];
    uc = min(uc < 0 ? 0 : uc, 1);
    const int nxt = uc ? cn.z : cn.x;
    const int nb2 = nxt > 0 ? nxt : 0;
    int nbt2 = s_bt[nb2];
    if (nbt2 < 0) nbt2 = 0;
    const int ipn = (nxt >= 0) ? s_ip[nbt2] : 0;
    const int ri  = s_rti[btc * 2 + ipn];

    const float* rp = s_rp + ri * 4;
    const float x = (dih[0] - rp[0]) * __builtin_amdgcn_rcpf(rp[2]);
    const float y = (dih[1] - rp[1]) * __builtin_amdgcn_rcpf(rp[3]);
    const float ix0 = floorf(x);
    const float iy0 = floorf(y);
    const float fx = x - ix0;
    const float fy = y - iy0;
    const int xs0 = wrap36((int)ix0 - 1);
    const int ys0 = wrap36((int)iy0 - 1);

    float wx[4], wy[4];
    crw(fx, wx);
    crw(fy, wy);

    const float* rt = rama_tables + (size_t)ri * NBIN * NBIN;
    float er = 0.0f;
    #pragma unroll
    for (int i = 0; i < 4; ++i) {
        int xi = xs0 + i;
        if (xi >= NBIN) xi -= NBIN;
        const float* rrow = rt + xi * NBIN;
        float r0, r1, r2, r3;
        if (ys0 <= NBIN - 4) {               // contiguous span: one 16B load
            const uf4 v = *(const uf4*)(rrow + ys0);
            r0 = v.x; r1 = v.y; r2 = v.z; r3 = v.w;
        } else {                             // wrap (~8% of lanes)
            int y1 = ys0 + 1, y2 = ys0 + 2, y3 = ys0 + 3;
            if (y1 >= NBIN) y1 -= NBIN;
            if (y2 >= NBIN) y2 -= NBIN;
            if (y3 >= NBIN) y3 -= NBIN;
            r0 = rrow[ys0]; r1 = rrow[y1]; r2 = rrow[y2]; r3 = rrow[y3];
        }
        er = fmaf(wx[i],
                  fmaf(wy[0], r0, fmaf(wy[1], r1, fmaf(wy[2], r2, wy[3] * r3))),
                  er);
    }
    float r_contrib = (tv[0] && tv[1]) ? er : 0.0f;

    // ---- omega (padded LDS row: no wraps) ----
    const int oi = s_ip[btc];
    const float z = (dih[2] - s_op[oi * 2 + 0]) * __builtin_amdgcn_rcpf(s_op[oi * 2 + 1]);
    const float iz0 = floorf(z);
    const float fz = z - iz0;
    const int izw = wrap36((int)iz0);
    float wz[4];
    crw(fz, wz);
    const float* ot = s_ot2 + oi * PADT + izw;
    float eo = wz[0] * ot[0] + wz[1] * ot[1] + wz[2] * ot[2] + wz[3] * ot[3];
    float o_contrib = tv[2] ? eo : 0.0f;

    // ---- reduce ----
    float r = r_contrib;
    float o = o_contrib;
    #pragma unroll
    for (int d = 32; d > 0; d >>= 1) {
        r += __shfl_down(r, d);
        o += __shfl_down(o, d);
    }
    const int wid = tid >> 6;
    if ((tid & 63) == 0) {
        swr[wid] = r;
        swo[wid] = o;
    }
    __syncthreads();
    if (tid < 64) {
        float R = (tid < 16) ? swr[tid] : 0.0f;
        float O = (tid < 16) ? swo[tid] : 0.0f;
        #pragma unroll
        for (int d = 8; d > 0; d >>= 1) {
            R += __shfl_down(R, d);
            O += __shfl_down(O, d);
        }
        if (tid == 0) {
            out[p]      = R;
            out[PN + p] = O;
        }
    }
}

extern "C" void kernel_launch(void* const* d_in, const int* in_sizes, int n_in,
                              void* d_out, int out_size, void* d_ws, size_t ws_size,
                              hipStream_t stream) {
    const float* coords        = (const float*)d_in[0];
    const int*   off           = (const int*)d_in[1];
    const int*   btype         = (const int*)d_in[2];
    const int*   conn          = (const int*)d_in[3];
    const int*   dsc           = (const int*)d_in[4];
    const int*   rama_tbl_ind  = (const int*)d_in[5];
    const int*   upper_conn    = (const int*)d_in[6];
    const int*   is_pro        = (const int*)d_in[7];
    const int*   tor_atoms     = (const int*)d_in[8];
    const float* rama_tables   = (const float*)d_in[9];
    const float* omega_tables  = (const float*)d_in[10];
    const float* rama_params   = (const float*)d_in[11];
    const float* omega_params  = (const float*)d_in[12];
    float* out = (float*)d_out;

    // One block per pose; every output element written exactly once ->
    // no memset, no atomics, single dispatch.
    bb_torsion_kernel<<<PN, 1024, 0, stream>>>(
        coords, off, btype, conn, dsc, rama_tbl_ind, upper_conn, is_pro,
        tor_atoms, rama_tables, omega_tables, rama_params, omega_params, out);
}